// Round 1
// baseline (423.402 us; speedup 1.0000x reference)
//
#include <hip/hip_runtime.h>

// NMS 3x3, replicate pad, strict >, max initialized at 0 (center tap zeroed).
// x: (8, 32, 512, 512) fp32. out = x * (x > max(0, 8 neighbors)).
//
// Memory-bound stencil. Block = 256 threads handles a 4x512 tile of one
// (b,c) image plane. 6 rows (tile + halo, row-clamped) staged in LDS with
// aligned float4 global loads -> ds_write_b128 (contiguous, conflict-free).
// Compute: each lane owns a column strip (stride-1 LDS reads across lanes,
// 2 lanes/bank = free). Clamped indices reproduce replicate padding: at the
// border the clamped neighbor equals the center, so x > m is false -> 0,
// exactly matching the reference.

#define IMG_W 512
#define IMG_H 512
#define TILE_H 4
#define THREADS 256
#define SROWS (TILE_H + 2)
#define SSTRIDE 520  // floats; multiple of 4 -> 16B-aligned rows

static_assert((SROWS * (IMG_W / 4)) % THREADS == 0, "staging divides evenly");
static_assert(IMG_W % THREADS == 0, "compute strips divide evenly");
static_assert(IMG_H % TILE_H == 0, "tiles divide evenly");

__global__ __launch_bounds__(THREADS)
void nms3x3_kernel(const float* __restrict__ x, float* __restrict__ out) {
    const int tile = blockIdx.x;   // 0 .. IMG_H/TILE_H - 1
    const int bc   = blockIdx.y;   // 0 .. B*C - 1
    const int h0   = tile * TILE_H;
    const float* img  = x   + (size_t)bc * IMG_H * IMG_W;
    float*       oimg = out + (size_t)bc * IMG_H * IMG_W;

    __shared__ float sh[SROWS * SSTRIDE];

    const int tid = threadIdx.x;

    // ---- Stage 6 rows (h0-1 .. h0+4, clamped) into LDS, float4 everywhere.
    constexpr int NVEC = SROWS * (IMG_W / 4);        // 768
    constexpr int ITERS = NVEC / THREADS;            // 3
#pragma unroll
    for (int k = 0; k < ITERS; ++k) {
        const int i  = tid + k * THREADS;
        const int r  = i >> 7;        // / (IMG_W/4)
        const int c4 = i & 127;       // % (IMG_W/4)
        int gh = h0 - 1 + r;
        gh = max(0, min(IMG_H - 1, gh));
        const float4 v = *(const float4*)(img + (size_t)gh * IMG_W + (c4 << 2));
        *(float4*)(&sh[r * SSTRIDE + (c4 << 2)]) = v;
    }
    __syncthreads();

    // ---- Compute: each lane does a 1-col x TILE_H strip; 2 strips per lane.
#pragma unroll
    for (int s = 0; s < IMG_W / THREADS; ++s) {
        const int c  = tid + s * THREADS;
        const int cl = (c == 0)         ? 0         : c - 1;
        const int cr = (c == IMG_W - 1) ? IMG_W - 1 : c + 1;

        float lv[SROWS], mv[SROWS], rv[SROWS];
#pragma unroll
        for (int rr = 0; rr < SROWS; ++rr) {
            lv[rr] = sh[rr * SSTRIDE + cl];
            mv[rr] = sh[rr * SSTRIDE + c];
            rv[rr] = sh[rr * SSTRIDE + cr];
        }
#pragma unroll
        for (int k = 0; k < TILE_H; ++k) {
            float mx = 0.0f;
            mx = fmaxf(mx, lv[k]);     mx = fmaxf(mx, lv[k + 1]); mx = fmaxf(mx, lv[k + 2]);
            mx = fmaxf(mx, mv[k]);                                 mx = fmaxf(mx, mv[k + 2]);
            mx = fmaxf(mx, rv[k]);     mx = fmaxf(mx, rv[k + 1]); mx = fmaxf(mx, rv[k + 2]);
            const float cen = mv[k + 1];
            oimg[(size_t)(h0 + k) * IMG_W + c] = (cen > mx) ? cen : 0.0f;
        }
    }
}

extern "C" void kernel_launch(void* const* d_in, const int* in_sizes, int n_in,
                              void* d_out, int out_size, void* d_ws, size_t ws_size,
                              hipStream_t stream) {
    const float* x  = (const float*)d_in[0];
    float* out      = (float*)d_out;
    dim3 grid(IMG_H / TILE_H, 8 * 32);   // 128 tiles x 256 planes = 32768 blocks
    nms3x3_kernel<<<grid, dim3(THREADS), 0, stream>>>(x, out);
}